// Round 2
// baseline (304.025 us; speedup 1.0000x reference)
//
#include <hip/hip_runtime.h>

// HungarianMatcher cost C[16,1500,2400] = 5*L1 + focal_class + 2*(-GIoU)
// v3: wave-per-row structure.
//  - block = 256 thr = 4 waves; wave w owns query n = blockIdx.x*4 + w and
//    writes its ENTIRE contiguous 9.6KB output row (block: 38.4KB linear)
//  - no grid.y tile split: focal table built exactly once per query (was 3x)
//  - NO __syncthreads: each wave builds + reads only its own s_fcl row;
//    compiler orders the ds_write->ds_read RAW via lgkmcnt (same array,
//    dynamic indices -> must-alias). Waves fully decoupled -> a SIMD's
//    resident waves desynchronize, store bursts overlap other waves' VALU.
//  - per iteration: lane owns 4 consecutive targets -> int4 cid load,
//    4x float4 box loads (L1/L2-hit, tboxes=38KB), 4 fp32 LDS gathers
//    (bank = cid%32, random -> ~2-way, free per m136), one float4 store
//  - floors: stores 230MB ~37us, VALU ~25us (33 ops/elem), reads ~8us L2
namespace {
constexpr int kBS = 16, kQ = 1500, kK = 256, kNT = 150;
constexpr int kT   = kBS * kNT;   // 2400 targets
constexpr int kN   = kBS * kQ;    // 24000 queries
constexpr int kQPB = 4;           // queries per block = 1 per wave
constexpr float kAlpha = 0.25f;
constexpr float kEps   = 1e-8f;
}

__global__ __launch_bounds__(256, 4)
void matcher_cost_kernel(const float* __restrict__ logits,   // [N,256]
                         const float* __restrict__ pboxes,   // [N,4] cxcywh
                         const float* __restrict__ tboxes,   // [T,4] cxcywh
                         const int*   __restrict__ tids,     // [T]
                         float* __restrict__ out)            // [N,T]
{
    __shared__ float s_fcl[kQPB][kK];   // 4 KB; stores (cc + 2) per (wave,class)

    const int tid  = threadIdx.x;
    const int wv   = tid >> 6;
    const int lane = tid & 63;
    const int n    = blockIdx.x * kQPB + wv;   // this wave's query row

    // query box first (wave-uniform), so the load is in flight early
    const float4 pb = *reinterpret_cast<const float4*>(pboxes + (size_t)n * 4);

    // ---- focal class-cost row for THIS wave's query (cc + 2.0 folded) ----
    const float* lrow = logits + (size_t)n * kK;
#pragma unroll
    for (int j = 0; j < kK / 64; ++j) {
        const int   c   = lane + 64 * j;
        const float x   = lrow[c];
        const float p   = __builtin_amdgcn_rcpf(1.0f + __expf(-x));
        const float omp = 1.0f - p;
        s_fcl[wv][c] = -kAlpha * omp * omp * __logf(p + kEps)
                     + (1.0f - kAlpha) * p * p * __logf(omp + kEps) + 2.0f;
    }
    // no barrier: wave reads only the row it wrote (lgkmcnt orders RAW)

    const float pcx = pb.x, pcy = pb.y, pw = pb.z, ph = pb.w;
    const float px1 = pcx - 0.5f * pw, px2 = pcx + 0.5f * pw;
    const float py1 = pcy - 0.5f * ph, py2 = pcy + 0.5f * ph;
    const float parea = pw * ph;

    const float4* __restrict__ tb4  = reinterpret_cast<const float4*>(tboxes);
    float* __restrict__        orow = out + (size_t)n * kT;

    auto group4 = [&](int t) {   // 4 consecutive targets [t, t+4)
        const int4 ci = *reinterpret_cast<const int4*>(tids + t);
        float4 res;
        float* rp = &res.x;
        const int cid[4] = {ci.x, ci.y, ci.z, ci.w};
#pragma unroll
        for (int e = 0; e < 4; ++e) {
            const float4 b  = tb4[t + e];
            const float  cc = s_fcl[wv][cid[e]];
            const float bcx = b.x, bcy = b.y, bw = b.z, bh = b.w;
            // L1 cost (cxcywh space) — fabs folds into add modifiers
            const float cb = fabsf(pcx - bcx) + fabsf(pcy - bcy)
                           + fabsf(pw - bw)  + fabsf(ph - bh);
            // overlap; enclose via identity ew = pw+bw-ow
            const float bx1 = fmaf(-0.5f, bw, bcx), bx2 = fmaf(0.5f, bw, bcx);
            const float by1 = fmaf(-0.5f, bh, bcy), by2 = fmaf(0.5f, bh, bcy);
            const float ow = fminf(px2, bx2) - fmaxf(px1, bx1);
            const float oh = fminf(py2, by2) - fmaxf(py1, by1);
            const float iw = fmaxf(ow, 0.0f), ih = fmaxf(oh, 0.0f);
            const float ew = (pw + bw) - ow,  eh = (ph + bh) - oh;
            const float inter = iw * ih;
            const float uni   = fmaf(bw, bh, parea) - inter;
            const float ear   = ew * eh;
            // out = 5*cb + (cc+2) - 2*(inter*ear + uni*uni)/(uni*ear)
            const float rr   = __builtin_amdgcn_rcpf(uni * ear);
            const float frac = fmaf(uni, uni, inter * ear) * rr;
            rp[e] = fmaf(-2.0f, frac, fmaf(5.0f, cb, cc));
        }
        *reinterpret_cast<float4*>(orow + t) = res;
    };

    // 2400 targets: 9 full 256-target chunks + 96-target tail (lanes 0..23)
#pragma unroll 3
    for (int it = 0; it < 9; ++it) group4(it * 256 + lane * 4);
    if (lane < 24) group4(2304 + lane * 4);
}

extern "C" void kernel_launch(void* const* d_in, const int* in_sizes, int n_in,
                              void* d_out, int out_size, void* d_ws, size_t ws_size,
                              hipStream_t stream) {
    const float* logits = (const float*)d_in[0];   // [16,1500,256]
    const float* pboxes = (const float*)d_in[1];   // [16,1500,4]
    const float* tboxes = (const float*)d_in[2];   // [2400,4]
    const int*   tids   = (const int*)d_in[3];     // [2400]
    float* out = (float*)d_out;                    // [16,1500,2400] fp32

    dim3 grid(kN / kQPB);   // 6000 blocks, 4 independent wave-rows each
    dim3 block(256);
    hipLaunchKernelGGL(matcher_cost_kernel, grid, block, 0, stream,
                       logits, pboxes, tboxes, tids, out);
}

// Round 4
// 266.881 us; speedup vs baseline: 1.1392x; 1.1392x over previous
//
#include <hip/hip_runtime.h>
#include <hip/hip_fp16.h>

// HungarianMatcher cost C[16,1500,2400] = 5*L1 + focal_class + 2*(-GIoU)
// v4 = v2 skeleton (targets in registers, fp16 transposed focal table,
// float4 stores) with the 3x preamble duplication removed:
//  - block = 256 thr, owns 8 queries x ALL 2400 targets (internal 3-tile loop)
//    -> focal table + logits read built ONCE per query (was 3x via grid.y)
//  - 3000 blocks (~2.9 resident epochs) keeps end-of-kernel tail <5%
//    (a 16q/1500-block merge would idle ~27% - packing arithmetic)
//  - per tile: thread owns 4 consecutive targets in regs (int4 + 4x float4,
//    L2-hot 38.4KB), one ds_read_b64 fetches class cost for 4 queries
//  - nontemporal float4 stores (via native ext_vector_type - the HIP
//    float4 class type is rejected by the builtin): output is write-once
// Floors: stores 230MB ~37us, VALU ~25us (34 ops/elem).

namespace {
constexpr int kBS = 16, kQ = 1500, kK = 256, kNT = 150;
constexpr int kT   = kBS * kNT;   // 2400
constexpr int kN   = kBS * kQ;    // 24000
constexpr int kQB  = 8;           // queries per block
constexpr float kAlpha = 0.25f;
constexpr float kEps   = 1e-8f;
typedef float floatx4 __attribute__((ext_vector_type(4)));
}

__global__ __launch_bounds__(256, 4)
void matcher_cost_kernel(const float* __restrict__ logits,   // [N,256]
                         const float* __restrict__ pboxes,   // [N,4] cxcywh
                         const float* __restrict__ tboxes,   // [T,4] cxcywh
                         const int*   __restrict__ tids,     // [T]
                         float* __restrict__ out)            // [N,T]
{
    // [class][q/2] half2, row stride 6 half2 = 24B (cols 4,5 pad). 6 KB.
    // gather addr = cid*24 + qg*8: 8B-aligned; random cid -> 16 bank-pair
    // starts, ~4-way expected (cheap per m136).
    __shared__ __align__(16) __half2 s_fcl[kK][6];

    const int tid = threadIdx.x;
    const int n0  = blockIdx.x * kQB;

    // ---- focal class-cost table (cc + 2.0 folded), thread = class ----
    {
        const float* lrow = logits + (size_t)n0 * kK + tid;
#pragma unroll
        for (int qp = 0; qp < kQB / 2; ++qp) {
            float c[2];
#pragma unroll
            for (int j = 0; j < 2; ++j) {
                const float x   = lrow[(2 * qp + j) * kK];
                const float p   = __builtin_amdgcn_rcpf(1.0f + __expf(-x));
                const float omp = 1.0f - p;
                c[j] = -kAlpha * omp * omp * __logf(p + kEps)
                     + (1.0f - kAlpha) * p * p * __logf(omp + kEps) + 2.0f;
            }
            s_fcl[tid][qp] = __floats2half2_rn(c[0], c[1]);
        }
    }
    __syncthreads();   // the only barrier; LDS read-only below

    const float4* __restrict__ tb4 = reinterpret_cast<const float4*>(tboxes);

    auto tilework = [&](int tbase) {   // 4 consecutive targets [tbase, tbase+4)
        const int4 ci = *reinterpret_cast<const int4*>(tids + tbase);
        const int cid[4] = {ci.x, ci.y, ci.z, ci.w};
        float bcx[4], bcy[4], bw[4], bh[4], bx1[4], bx2[4], by1[4], by2[4];
#pragma unroll
        for (int e = 0; e < 4; ++e) {
            const float4 b = tb4[tbase + e];
            bcx[e] = b.x; bcy[e] = b.y; bw[e] = b.z; bh[e] = b.w;
            bx1[e] = fmaf(-0.5f, bw[e], bcx[e]);  bx2[e] = fmaf(0.5f, bw[e], bcx[e]);
            by1[e] = fmaf(-0.5f, bh[e], bcy[e]);  by2[e] = fmaf(0.5f, bh[e], bcy[e]);
        }
        float* __restrict__ ob = out + (size_t)n0 * kT + tbase;

#pragma unroll
        for (int qg = 0; qg < kQB / 4; ++qg) {
            uint2 ccr[4];   // one b64 per target = class cost for 4 queries
#pragma unroll
            for (int e = 0; e < 4; ++e)
                ccr[e] = *reinterpret_cast<const uint2*>(&s_fcl[cid[e]][qg * 2]);

#pragma unroll
            for (int qi = 0; qi < 4; ++qi) {
                const int q = qg * 4 + qi;
                // block-uniform query box -> s_load
                const float4 pb = *reinterpret_cast<const float4*>(
                                      pboxes + (size_t)(n0 + q) * 4);
                const float pcx = pb.x, pcy = pb.y, pw = pb.z, ph = pb.w;
                const float px1 = fmaf(-0.5f, pw, pcx), px2 = fmaf(0.5f, pw, pcx);
                const float py1 = fmaf(-0.5f, ph, pcy), py2 = fmaf(0.5f, ph, pcy);
                const float parea = pw * ph;

                floatx4 res;
#pragma unroll
                for (int e = 0; e < 4; ++e) {
                    const unsigned u  = (qi < 2) ? ccr[e].x : ccr[e].y;  // qi const
                    const __half2 h2  = *reinterpret_cast<const __half2*>(&u);
                    const float   cc  = (qi & 1) ? __high2float(h2) : __low2float(h2);
                    // L1 cost (cxcywh space)
                    const float cb = fabsf(pcx - bcx[e]) + fabsf(pcy - bcy[e])
                                   + fabsf(pw - bw[e])  + fabsf(ph - bh[e]);
                    // overlap; enclose via identity ew = pw+bw-ow
                    const float ow = fminf(px2, bx2[e]) - fmaxf(px1, bx1[e]);
                    const float oh = fminf(py2, by2[e]) - fmaxf(py1, by1[e]);
                    const float iw = fmaxf(ow, 0.0f), ih = fmaxf(oh, 0.0f);
                    const float ew = (pw + bw[e]) - ow, eh = (ph + bh[e]) - oh;
                    const float inter = iw * ih;
                    const float uni   = fmaf(bw[e], bh[e], parea) - inter;
                    const float ear   = ew * eh;
                    // out = 5cb + (cc+2) - 2*(inter*ear + uni*uni)/(uni*ear)
                    const float rr   = __builtin_amdgcn_rcpf(uni * ear);
                    const float frac = fmaf(uni, uni, inter * ear) * rr;
                    res[e] = fmaf(-2.0f, frac, fmaf(5.0f, cb, cc));
                }
                __builtin_nontemporal_store(
                    res, reinterpret_cast<floatx4*>(ob + (size_t)q * kT));
            }
        }
    };

    // tiles: [0,1024) [1024,2048) [2048,2400)
    const int o4 = tid << 2;
    tilework(o4);
    tilework(1024 + o4);
    if (o4 < 352) tilework(2048 + o4);   // waves 2,3 retire early
}

extern "C" void kernel_launch(void* const* d_in, const int* in_sizes, int n_in,
                              void* d_out, int out_size, void* d_ws, size_t ws_size,
                              hipStream_t stream) {
    const float* logits = (const float*)d_in[0];   // [16,1500,256]
    const float* pboxes = (const float*)d_in[1];   // [16,1500,4]
    const float* tboxes = (const float*)d_in[2];   // [2400,4]
    const int*   tids   = (const int*)d_in[3];     // [2400]
    float* out = (float*)d_out;                    // [16,1500,2400] fp32

    dim3 grid(kN / kQB);   // 3000 blocks
    dim3 block(256);
    hipLaunchKernelGGL(matcher_cost_kernel, grid, block, 0, stream,
                       logits, pboxes, tboxes, tids, out);
}